// Round 5
// baseline (1997.270 us; speedup 1.0000x reference)
//
#include <hip/hip_runtime.h>
#include <math.h>

#define TOKENS 8192
#define EDIM   1024
#define TSEQ   2048
#define NEXP   2048

typedef __attribute__((ext_vector_type(8))) short short8;
typedef __attribute__((ext_vector_type(4))) float f32x4;

__device__ __forceinline__ short f2bf(float f) {
  union { float f; unsigned u; } c; c.f = f;
  unsigned r = c.u + 0x7fffu + ((c.u >> 16) & 1u);
  return (short)(r >> 16);
}
__device__ __forceinline__ float bf2f(short h) {
  union { unsigned u; float f; } c; c.u = ((unsigned)(unsigned short)h) << 16;
  return c.f;
}
// split fp32 into 3 bf16 planes: a ≈ p0 + p1 + p2 (rel err ~2^-27)
__device__ __forceinline__ void split3(float a, short& p0, short& p1, short& p2) {
  p0 = f2bf(a);
  float r = a - bf2f(p0);
  p1 = f2bf(r);
  p2 = f2bf(r - bf2f(p1));
}
// split fp32 into 2 bf16 planes: a ≈ p0 + p1 (rel err ~2^-16)
__device__ __forceinline__ void split2(float a, short& p0, short& p1) {
  p0 = f2bf(a);
  p1 = f2bf(a - bf2f(p0));
}

// ---------------- LayerNorm: fp32 in -> optional bf16 plane + fp32 out ----
__global__ __launch_bounds__(256) void ln_kernel(const float* __restrict__ x,
    const float* __restrict__ g, const float* __restrict__ b,
    short* __restrict__ obf, float* __restrict__ of32)
{
  const int row = blockIdx.x;
  const int t = threadIdx.x, lane = t & 63, w = t >> 6;
  const float4 v = ((const float4*)(x + (size_t)row * EDIM))[t];
  __shared__ float lds[4];
  float s = v.x + v.y + v.z + v.w;
  #pragma unroll
  for (int m = 32; m >= 1; m >>= 1) s += __shfl_xor(s, m);
  if (lane == 0) lds[w] = s;
  __syncthreads();
  const float mu = (lds[0] + lds[1] + lds[2] + lds[3]) * (1.f / EDIM);
  __syncthreads();
  const float d0 = v.x - mu, d1 = v.y - mu, d2 = v.z - mu, d3 = v.w - mu;
  float sq = d0 * d0 + d1 * d1 + d2 * d2 + d3 * d3;
  #pragma unroll
  for (int m = 32; m >= 1; m >>= 1) sq += __shfl_xor(sq, m);
  if (lane == 0) lds[w] = sq;
  __syncthreads();
  const float var = (lds[0] + lds[1] + lds[2] + lds[3]) * (1.f / EDIM);
  const float rstd = rsqrtf(var + 1e-5f);
  const float4 gg = ((const float4*)g)[t];
  const float4 bb = ((const float4*)b)[t];
  const float y0 = d0 * rstd * gg.x + bb.x;
  const float y1 = d1 * rstd * gg.y + bb.y;
  const float y2 = d2 * rstd * gg.z + bb.z;
  const float y3 = d3 * rstd * gg.w + bb.w;
  if (obf) {
    unsigned long long pk =
        (unsigned long long)(unsigned short)f2bf(y0)
      | ((unsigned long long)(unsigned short)f2bf(y1) << 16)
      | ((unsigned long long)(unsigned short)f2bf(y2) << 32)
      | ((unsigned long long)(unsigned short)f2bf(y3) << 48);
    *(unsigned long long*)(obf + (size_t)row * EDIM + t * 4) = pk;
  }
  ((float4*)(of32 + (size_t)row * EDIM))[t] = make_float4(y0, y1, y2, y3);
}

// ---------------- W (KxN fp32) -> 3 bf16 planes Wt[p][N][K] ---------------
__global__ __launch_bounds__(256) void wsplit_kernel(const float* __restrict__ W,
    short* __restrict__ Wt, int K, int N)
{
  __shared__ float tile[32][33];
  const int n0 = blockIdx.x * 32, k0 = blockIdx.y * 32;
  const int tx = threadIdx.x & 31, ty = threadIdx.x >> 5;
  #pragma unroll
  for (int i = 0; i < 4; i++)
    tile[ty * 4 + i][tx] = W[(size_t)(k0 + ty * 4 + i) * N + n0 + tx];
  __syncthreads();
  const size_t PS = (size_t)N * K;
  #pragma unroll
  for (int i = 0; i < 4; i++) {
    short p0, p1, p2;
    split3(tile[tx][ty * 4 + i], p0, p1, p2);
    const size_t idx = (size_t)(n0 + ty * 4 + i) * K + k0 + tx;
    Wt[idx] = p0; Wt[PS + idx] = p1; Wt[2 * PS + idx] = p2;
  }
}

// ---------------- W (KxN fp32) -> single bf16 plane (NxK) -----------------
__global__ __launch_bounds__(256) void wconv_kernel(const float* __restrict__ W,
    short* __restrict__ Wt, int K, int N)
{
  __shared__ float tile[32][33];
  const int n0 = blockIdx.x * 32, k0 = blockIdx.y * 32;
  const int tx = threadIdx.x & 31, ty = threadIdx.x >> 5;
  #pragma unroll
  for (int i = 0; i < 4; i++)
    tile[ty * 4 + i][tx] = W[(size_t)(k0 + ty * 4 + i) * N + n0 + tx];
  __syncthreads();
  #pragma unroll
  for (int i = 0; i < 4; i++)
    Wt[(size_t)(n0 + ty * 4 + i) * K + k0 + tx] = f2bf(tile[tx][ty * 4 + i]);
}

// ---------------- flat fp32 [M*K] -> 3 bf16 planes (same layout) ----------
__global__ __launch_bounds__(256) void asplit_kernel(const float* __restrict__ src,
    short* __restrict__ dst, size_t PS)
{
  const size_t g8 = ((size_t)blockIdx.x * 256 + threadIdx.x) * 8;
  float v[8];
  *(float4*)&v[0] = *(const float4*)(src + g8);
  *(float4*)&v[4] = *(const float4*)(src + g8 + 4);
  short pl[3][8];
  #pragma unroll
  for (int j = 0; j < 8; j++) split3(v[j], pl[0][j], pl[1][j], pl[2][j]);
  *(short8*)(dst + g8)          = *(short8*)&pl[0][0];
  *(short8*)(dst + PS + g8)     = *(short8*)&pl[1][0];
  *(short8*)(dst + 2 * PS + g8) = *(short8*)&pl[2][0];
}

// ---------------- K section of qkvf -> 3 bf16 planes [3][8192][1024] ------
__global__ __launch_bounds__(256) void ksplit_kernel(const float* __restrict__ qkvf,
    short* __restrict__ Kp)
{
  const size_t gid = (size_t)blockIdx.x * 256 + threadIdx.x;
  const int tok = (int)(gid >> 7);
  const int c = (int)(gid & 127) * 8;
  const float* src = qkvf + (size_t)tok * 3072 + 1024 + c;
  float v[8];
  *(float4*)&v[0] = *(const float4*)src;
  *(float4*)&v[4] = *(const float4*)(src + 4);
  short pl[3][8];
  #pragma unroll
  for (int j = 0; j < 8; j++) split3(v[j], pl[0][j], pl[1][j], pl[2][j]);
  const size_t PS = (size_t)TOKENS * EDIM;
  const size_t dst = (size_t)tok * EDIM + c;
  *(short8*)(Kp + dst)          = *(short8*)&pl[0][0];
  *(short8*)(Kp + PS + dst)     = *(short8*)&pl[1][0];
  *(short8*)(Kp + 2 * PS + dst) = *(short8*)&pl[2][0];
}

// ---------------- V section -> 3 transposed planes [3][bh][d(64)][t(2048)]
__global__ __launch_bounds__(256) void vtrans_kernel(const float* __restrict__ qkvf,
    short* __restrict__ Vt)
{
  __shared__ float tile[32][33];
  const int bh = blockIdx.x;
  const int b = bh >> 4, h = bh & 15;
  const int t0 = blockIdx.y * 32;
  const int d0 = blockIdx.z * 32;
  const int tx = threadIdx.x & 31, ty = threadIdx.x >> 5;
  #pragma unroll
  for (int i = 0; i < 4; i++)
    tile[ty * 4 + i][tx] =
        qkvf[(size_t)(b * TSEQ + t0 + ty * 4 + i) * 3072 + 2048 + h * 64 + d0 + tx];
  __syncthreads();
  const size_t PS = (size_t)64 * 64 * TSEQ;
  #pragma unroll
  for (int i = 0; i < 4; i++) {
    short p0, p1, p2;
    split3(tile[tx][ty * 4 + i], p0, p1, p2);
    const size_t idx = (size_t)(bh * 64 + d0 + ty * 4 + i) * TSEQ + t0 + tx;
    Vt[idx] = p0; Vt[PS + idx] = p1; Vt[2 * PS + idx] = p2;
  }
}

// ---------------- high-precision GEMM: C = Aplanes * Bplanes^T + bias -----
// Both A and B pre-split into 3 bf16 planes. 6 MFMA products per frag.
// Unpadded XOR-swizzled LDS (49152 B -> 3 blocks/CU) + T3-style 2-phase
// register double-buffer: frag-read(k) -> issue loads(k+1) -> MFMA(k) ->
// barrier -> regs->LDS -> barrier.  NO launch_bounds min-wave clamp
// (round-3 lesson: it forced an 84-VGPR budget and spilled acc to scratch).
template<int ADD_RES>
__global__ __launch_bounds__(256) void gemm_hp(const short* __restrict__ Ap, size_t astride,
    const short* __restrict__ Bp, size_t bstride, const float* __restrict__ bias,
    const float* __restrict__ resid, float* __restrict__ outp,
    int M, int N, int K)
{
  __shared__ short As[3][128][32];   // 24576 B
  __shared__ short Bs[3][128][32];   // 24576 B
  const int m0 = blockIdx.y * 128, n0 = blockIdx.x * 128;
  const int t = threadIdx.x;
  const int lane = t & 63, w = t >> 6;
  const int wm = w >> 1, wn = w & 1;
  const int lo = lane & 15, hi = lane >> 4;
  const int rr = t >> 2;                            // staging row (0..63, +u*64)
  const int cj = t & 3;                             // staged chunk id
  const int crw = (rr & 3) ^ ((rr >> 2) & 3);       // row swizzle code (u-invariant)
  const int wc8 = ((cj ^ crw)) * 8;                 // swizzled write offset (shorts)
  const int rc8 = ((hi ^ (lo & 3) ^ ((lo >> 2) & 3))) * 8;  // swizzled read offset
  f32x4 acc[4][4];
  #pragma unroll
  for (int i = 0; i < 4; i++)
    #pragma unroll
    for (int j = 0; j < 4; j++)
      acc[i][j] = (f32x4){0.f, 0.f, 0.f, 0.f};

  const short* aptr = Ap + (size_t)(m0 + rr) * K + cj * 8;
  const short* bptr = Bp + (size_t)(n0 + rr) * K + cj * 8;
  uint4 areg[3][2], breg[3][2];

  // prologue: tile 0 -> regs -> LDS
  #pragma unroll
  for (int p = 0; p < 3; p++)
    #pragma unroll
    for (int u = 0; u < 2; u++) {
      areg[p][u] = *(const uint4*)(aptr + (size_t)p * astride + (size_t)u * 64 * K);
      breg[p][u] = *(const uint4*)(bptr + (size_t)p * bstride + (size_t)u * 64 * K);
    }
  aptr += 32; bptr += 32;
  #pragma unroll
  for (int p = 0; p < 3; p++)
    #pragma unroll
    for (int u = 0; u < 2; u++) {
      *(uint4*)&As[p][u * 64 + rr][wc8] = areg[p][u];
      *(uint4*)&Bs[p][u * 64 + rr][wc8] = breg[p][u];
    }
  __syncthreads();

  for (int k0 = 0; k0 < K; k0 += 32) {
    short8 af[3][4], bf[3][4];
    #pragma unroll
    for (int p = 0; p < 3; p++)
      #pragma unroll
      for (int i = 0; i < 4; i++) {
        af[p][i] = *(const short8*)(&As[p][wm * 64 + i * 16 + lo][rc8]);
        bf[p][i] = *(const short8*)(&Bs[p][wn * 64 + i * 16 + lo][rc8]);
      }
    const int more = (k0 + 32 < K);
    if (more) {   // issue next-tile loads; latency hides under the MFMA cluster
      #pragma unroll
      for (int p = 0; p < 3; p++)
        #pragma unroll
        for (int u = 0; u < 2; u++) {
          areg[p][u] = *(const uint4*)(aptr + (size_t)p * astride + (size_t)u * 64 * K);
          breg[p][u] = *(const uint4*)(bptr + (size_t)p * bstride + (size_t)u * 64 * K);
        }
      aptr += 32; bptr += 32;
    }
    __builtin_amdgcn_s_setprio(1);
    #pragma unroll
    for (int i = 0; i < 4; i++)
      #pragma unroll
      for (int j = 0; j < 4; j++) {
        acc[i][j] = __builtin_amdgcn_mfma_f32_16x16x32_bf16(af[0][i], bf[0][j], acc[i][j], 0, 0, 0);
        acc[i][j] = __builtin_amdgcn_mfma_f32_16x16x32_bf16(af[0][i], bf[1][j], acc[i][j], 0, 0, 0);
        acc[i][j] = __builtin_amdgcn_mfma_f32_16x16x32_bf16(af[1][i], bf[0][j], acc[i][j], 0, 0, 0);
        acc[i][j] = __builtin_amdgcn_mfma_f32_16x16x32_bf16(af[1][i], bf[1][j], acc[i][j], 0, 0, 0);
        acc[i][j] = __builtin_amdgcn_mfma_f32_16x16x32_bf16(af[0][i], bf[2][j], acc[i][j], 0, 0, 0);
        acc[i][j] = __builtin_amdgcn_mfma_f32_16x16x32_bf16(af[2][i], bf[0][j], acc[i][j], 0, 0, 0);
      }
    __builtin_amdgcn_s_setprio(0);
    if (more) {
      __syncthreads();   // all waves done reading LDS tile k
      #pragma unroll
      for (int p = 0; p < 3; p++)
        #pragma unroll
        for (int u = 0; u < 2; u++) {
          *(uint4*)&As[p][u * 64 + rr][wc8] = areg[p][u];
          *(uint4*)&Bs[p][u * 64 + rr][wc8] = breg[p][u];
        }
      __syncthreads();   // tile k+1 staged
    }
  }
  #pragma unroll
  for (int i = 0; i < 4; i++)
    #pragma unroll
    for (int j = 0; j < 4; j++)
      #pragma unroll
      for (int r = 0; r < 4; r++) {
        const int gm = m0 + wm * 64 + i * 16 + hi * 4 + r;
        const int gn = n0 + wn * 64 + j * 16 + lo;
        float v = acc[i][j][r] + bias[gn];
        if (ADD_RES) v += resid[(size_t)gm * N + gn];
        outp[(size_t)gm * N + gn] = v;
      }
}

// ---------------- high-precision flash attention (causal) -----------------
// Fixed-max softmax (scores bounded), deferred l-reduction, 2-plane P,
// register-prefetched K/V staging, conflict-free 40-pad LDS.
__global__ __launch_bounds__(256) void attn_hp(const float* __restrict__ qkvf,
    const short* __restrict__ Kp, const short* __restrict__ Vt,
    float* __restrict__ attno)
{
  const int bh = blockIdx.x;
  const int b = bh >> 4, h = bh & 15;
  const int qb0 = blockIdx.y * 64;
  const int t = threadIdx.x, lane = t & 63, w = t >> 6;
  const int lo = lane & 15, hi = lane >> 4;
  __shared__ short Ks[3][32][72];    // 13824 B
  __shared__ short Vs[3][64][40];    // 15360 B, transposed: Vs[p][dim][key]
  __shared__ short Ps[2][4][16][40]; // 10240 B -> total 39424 B: 4 blocks/CU
  const size_t base = (size_t)b * TSEQ * 3072;
  const size_t PSK = (size_t)TOKENS * EDIM;
  const size_t PSV = (size_t)64 * 64 * TSEQ;
  const int qw0 = qb0 + w * 16;
  short8 qf[3][2];
  #pragma unroll
  for (int c = 0; c < 2; c++) {
    const float* qp = qkvf + base + (size_t)(qw0 + lo) * 3072 + h * 64 + c * 32 + hi * 8;
    float qv[8];
    *(float4*)&qv[0] = *(const float4*)qp;
    *(float4*)&qv[4] = *(const float4*)(qp + 4);
    #pragma unroll
    for (int j = 0; j < 8; j++) {
      short s0, s1, s2;
      split3(qv[j] * 0.125f, s0, s1, s2);   // exact pow2 pre-scale
      qf[0][c][j] = s0; qf[1][c][j] = s1; qf[2][c][j] = s2;
    }
  }
  float l_r[4] = {0.f, 0.f, 0.f, 0.f};
  f32x4 o[4];
  #pragma unroll
  for (int nb = 0; nb < 4; nb++) o[nb] = (f32x4){0.f, 0.f, 0.f, 0.f};

  const int key = t >> 3, c0 = (t & 7) * 8;
  const int dv = t >> 2, kc = (t & 3) * 8;
  const short* kbase = Kp + (size_t)(b * TSEQ + key) * EDIM + h * 64 + c0;
  const short* vbase = Vt + (size_t)(bh * 64 + dv) * TSEQ + kc;
  short8 kreg0 = *(const short8*)kbase;
  short8 kreg1 = *(const short8*)(kbase + PSK);
  short8 kreg2 = *(const short8*)(kbase + 2 * PSK);
  short8 vreg0 = *(const short8*)vbase;
  short8 vreg1 = *(const short8*)(vbase + PSV);
  short8 vreg2 = *(const short8*)(vbase + 2 * PSV);

  const int ntiles = 2 * blockIdx.y + 2;
  for (int tile = 0; tile < ntiles; tile++) {
    const int kt0 = tile * 32;
    __syncthreads();                 // prior compute done reading LDS
    *(short8*)&Ks[0][key][c0] = kreg0;
    *(short8*)&Ks[1][key][c0] = kreg1;
    *(short8*)&Ks[2][key][c0] = kreg2;
    *(short8*)&Vs[0][dv][kc] = vreg0;
    *(short8*)&Vs[1][dv][kc] = vreg1;
    *(short8*)&Vs[2][dv][kc] = vreg2;
    __syncthreads();                 // tile staged
    if (tile + 1 < ntiles) {         // prefetch next tile; latency hides under MFMA
      const short* kp = kbase + (size_t)(tile + 1) * 32 * EDIM;
      const short* vp = vbase + (tile + 1) * 32;
      kreg0 = *(const short8*)kp;
      kreg1 = *(const short8*)(kp + PSK);
      kreg2 = *(const short8*)(kp + 2 * PSK);
      vreg0 = *(const short8*)vp;
      vreg1 = *(const short8*)(vp + PSV);
      vreg2 = *(const short8*)(vp + 2 * PSV);
    }
    if (kt0 <= qw0 + 15) {
      f32x4 s[2];
      __builtin_amdgcn_s_setprio(1);
      #pragma unroll
      for (int kb = 0; kb < 2; kb++) {
        f32x4 z = (f32x4){0.f, 0.f, 0.f, 0.f};
        #pragma unroll
        for (int c = 0; c < 2; c++) {
          const short8 kf0 = *(const short8*)(&Ks[0][kb * 16 + lo][c * 32 + hi * 8]);
          const short8 kf1 = *(const short8*)(&Ks[1][kb * 16 + lo][c * 32 + hi * 8]);
          const short8 kf2 = *(const short8*)(&Ks[2][kb * 16 + lo][c * 32 + hi * 8]);
          z = __builtin_amdgcn_mfma_f32_16x16x32_bf16(qf[0][c], kf0, z, 0, 0, 0);
          z = __builtin_amdgcn_mfma_f32_16x16x32_bf16(qf[0][c], kf1, z, 0, 0, 0);
          z = __builtin_amdgcn_mfma_f32_16x16x32_bf16(qf[1][c], kf0, z, 0, 0, 0);
          z = __builtin_amdgcn_mfma_f32_16x16x32_bf16(qf[1][c], kf1, z, 0, 0, 0);
          z = __builtin_amdgcn_mfma_f32_16x16x32_bf16(qf[0][c], kf2, z, 0, 0, 0);
          z = __builtin_amdgcn_mfma_f32_16x16x32_bf16(qf[2][c], kf0, z, 0, 0, 0);
        }
        s[kb] = z;
      }
      __builtin_amdgcn_s_setprio(0);
      // fixed-max softmax: exp(s), per-lane l partials (no cross-lane ops here)
      #pragma unroll
      for (int r = 0; r < 4; r++) {
        const int qg = qw0 + hi * 4 + r;
        #pragma unroll
        for (int kb = 0; kb < 2; kb++) {
          const int kg = kt0 + kb * 16 + lo;
          float v = s[kb][r];
          v = (kg > qg) ? -1e30f : v;
          const float pv = __expf(v);
          s[kb][r] = pv;
          l_r[r] += pv;
        }
      }
      #pragma unroll
      for (int kb = 0; kb < 2; kb++)
        #pragma unroll
        for (int r = 0; r < 4; r++) {
          short p0, p1;
          split2(s[kb][r], p0, p1);
          Ps[0][w][hi * 4 + r][kb * 16 + lo] = p0;
          Ps[1][w][hi * 4 + r][kb * 16 + lo] = p1;
        }
      __threadfence_block();   // intra-wave LDS RAW ordering (C->A layout)
      const short8 pf0 = *(const short8*)(&Ps[0][w][lo][hi * 8]);
      const short8 pf1 = *(const short8*)(&Ps[1][w][lo][hi * 8]);
      __builtin_amdgcn_s_setprio(1);
      #pragma unroll
      for (int nb = 0; nb < 4; nb++) {
        const short8 vb0 = *(const short8*)(&Vs[0][nb * 16 + lo][hi * 8]);
        const short8 vb1 = *(const short8*)(&Vs[1][nb * 16 + lo][hi * 8]);
        const short8 vb2 = *(const short8*)(&Vs[2][nb * 16 + lo][hi * 8]);
        o[nb] = __builtin_amdgcn_mfma_f32_16x16x32_bf16(pf0, vb0, o[nb], 0, 0, 0);
        o[nb] = __builtin_amdgcn_mfma_f32_16x16x32_bf16(pf0, vb1, o[nb], 0, 0, 0);
        o[nb] = __builtin_amdgcn_mfma_f32_16x16x32_bf16(pf1, vb0, o[nb], 0, 0, 0);
        o[nb] = __builtin_amdgcn_mfma_f32_16x16x32_bf16(pf1, vb1, o[nb], 0, 0, 0);
        o[nb] = __builtin_amdgcn_mfma_f32_16x16x32_bf16(pf0, vb2, o[nb], 0, 0, 0);
      }
      __builtin_amdgcn_s_setprio(0);
    }
  }
  // deferred l reduction: one 4-step shuffle per r for the whole block
  #pragma unroll
  for (int r = 0; r < 4; r++)
    #pragma unroll
    for (int mm = 8; mm >= 1; mm >>= 1) l_r[r] += __shfl_xor(l_r[r], mm);
  #pragma unroll
  for (int nb = 0; nb < 4; nb++)
    #pragma unroll
    for (int r = 0; r < 4; r++) {
      const int tok = qw0 + hi * 4 + r;
      attno[(size_t)(b * TSEQ + tok) * EDIM + h * 64 + nb * 16 + lo] = o[nb][r] / l_r[r];
    }
}

// ---------------- plain bf16 GEMM (gate logits): fp32 out ----------------
__global__ __launch_bounds__(256) void gemm_bf16(const short* __restrict__ A,
    const short* __restrict__ Bt, const float* __restrict__ bias,
    float* __restrict__ outp, int M, int N, int K)
{
  __shared__ short As[128][72];
  __shared__ short Bs[128][72];
  const int m0 = blockIdx.y * 128, n0 = blockIdx.x * 128;
  const int t = threadIdx.x;
  const int lane = t & 63, w = t >> 6;
  const int wm = w >> 1, wn = w & 1;
  const int lo = lane & 15, hi = lane >> 4;
  f32x4 acc[4][4];
  #pragma unroll
  for (int i = 0; i < 4; i++)
    #pragma unroll
    for (int j = 0; j < 4; j++)
      acc[i][j] = (f32x4){0.f, 0.f, 0.f, 0.f};
  for (int k0 = 0; k0 < K; k0 += 64) {
    #pragma unroll
    for (int c = 0; c < 4; c++) {
      const int cc = t + 256 * c;
      const int row = cc >> 3, col = (cc & 7) * 8;
      *(uint4*)(&As[row][col]) = *(const uint4*)(A + (size_t)(m0 + row) * K + k0 + col);
      *(uint4*)(&Bs[row][col]) = *(const uint4*)(Bt + (size_t)(n0 + row) * K + k0 + col);
    }
    __syncthreads();
    #pragma unroll
    for (int kk = 0; kk < 2; kk++) {
      short8 af[4], bf[4];
      #pragma unroll
      for (int i = 0; i < 4; i++) {
        af[i] = *(const short8*)(&As[wm * 64 + i * 16 + lo][kk * 32 + hi * 8]);
        bf[i] = *(const short8*)(&Bs[wn * 64 + i * 16 + lo][kk * 32 + hi * 8]);
      }
      #pragma unroll
      for (int i = 0; i < 4; i++)
        #pragma unroll
        for (int j = 0; j < 4; j++)
          acc[i][j] = __builtin_amdgcn_mfma_f32_16x16x32_bf16(af[i], bf[j], acc[i][j], 0, 0, 0);
    }
    __syncthreads();
  }
  #pragma unroll
  for (int i = 0; i < 4; i++)
    #pragma unroll
    for (int j = 0; j < 4; j++)
      #pragma unroll
      for (int r = 0; r < 4; r++) {
        const int gm = m0 + wm * 64 + i * 16 + hi * 4 + r;
        const int gn = n0 + wn * 64 + j * 16 + lo;
        outp[(size_t)gm * N + gn] = acc[i][j][r] + bias[gn];
      }
}

// ---------------- gate argmax with exact fp32 rescore of near-ties --------
__global__ __launch_bounds__(256) void gate_argmax(const float* __restrict__ logits,
    const float* __restrict__ h2f, const float* __restrict__ gw,
    const float* __restrict__ gb, int* __restrict__ eidx)
{
  const int token = blockIdx.x;
  const int t = threadIdx.x, lane = t & 63, w = t >> 6;
  const float* row = logits + (size_t)token * NEXP;
  float bm = -1e30f;
  #pragma unroll
  for (int c = 0; c < 8; c++) bm = fmaxf(bm, row[t + 256 * c]);
  #pragma unroll
  for (int m = 32; m >= 1; m >>= 1) bm = fmaxf(bm, __shfl_xor(bm, m));
  __shared__ float wred[4];
  __shared__ int cnt;
  __shared__ int cand[16];
  __shared__ float sred[4];
  if (t == 0) cnt = 0;
  if (lane == 0) wred[w] = bm;
  __syncthreads();
  const float maxv = fmaxf(fmaxf(wred[0], wred[1]), fmaxf(wred[2], wred[3]));
  const float thr = maxv - 0.03f;
  #pragma unroll
  for (int c = 0; c < 8; c++) {
    const int e = t + 256 * c;
    if (row[e] > thr) {
      const int p = atomicAdd(&cnt, 1);
      if (p < 16) cand[p] = e;
    }
  }
  __syncthreads();
  const int nc = cnt < 16 ? cnt : 16;
  if (nc == 1) {
    if (t == 0) eidx[token] = cand[0];
    return;
  }
  const float* xr = h2f + (size_t)token * EDIM;
  int best = NEXP; float bs = -1e30f;
  for (int c = 0; c < nc; c++) {
    const int e = cand[c];
    float p = 0.f;
    #pragma unroll
    for (int ii = 0; ii < 4; ii++) {
      const int i = t + 256 * ii;
      p += xr[i] * gw[(size_t)i * NEXP + e];
    }
    #pragma unroll
    for (int m = 32; m >= 1; m >>= 1) p += __shfl_xor(p, m);
    if (lane == 0) sred[w] = p;
    __syncthreads();
    const float s = sred[0] + sred[1] + sred[2] + sred[3] + gb[e];
    if (s > bs || (s == bs && e < best)) { bs = s; best = e; }
    __syncthreads();
  }
  if (t == 0) eidx[token] = best;
}

// ---------------- MoE expert apply (fp32, exact GELU), + residual --------
__global__ __launch_bounds__(256) void moe_kernel(const float* __restrict__ h2f,
    const int* __restrict__ eidx, const float* __restrict__ w1,
    const float* __restrict__ b1, const float* __restrict__ w2,
    const float* __restrict__ b2, float* __restrict__ out)
{
  const int token = blockIdx.x;
  const int t = threadIdx.x, lane = t & 63, w = t >> 6;
  const int e = eidx[token];
  const float* xr = h2f + (size_t)token * EDIM;
  const float* w1e = w1 + (size_t)e * (EDIM * 16);
  float acc[16];
  #pragma unroll
  for (int hh = 0; hh < 16; hh++) acc[hh] = 0.f;
  #pragma unroll
  for (int ii = 0; ii < 4; ii++) {
    const int i = t + 256 * ii;
    const float xi = xr[i];
    const float4* wr = (const float4*)(w1e + (size_t)i * 16);
    const float4 r0 = wr[0], r1 = wr[1], r2 = wr[2], r3 = wr[3];
    acc[0] = fmaf(xi, r0.x, acc[0]);  acc[1] = fmaf(xi, r0.y, acc[1]);
    acc[2] = fmaf(xi, r0.z, acc[2]);  acc[3] = fmaf(xi, r0.w, acc[3]);
    acc[4] = fmaf(xi, r1.x, acc[4]);  acc[5] = fmaf(xi, r1.y, acc[5]);
    acc[6] = fmaf(xi, r1.z, acc[6]);  acc[7] = fmaf(xi, r1.w, acc[7]);
    acc[8] = fmaf(xi, r2.x, acc[8]);  acc[9] = fmaf(xi, r2.y, acc[9]);
    acc[10] = fmaf(xi, r2.z, acc[10]); acc[11] = fmaf(xi, r2.w, acc[11]);
    acc[12] = fmaf(xi, r3.x, acc[12]); acc[13] = fmaf(xi, r3.y, acc[13]);
    acc[14] = fmaf(xi, r3.z, acc[14]); acc[15] = fmaf(xi, r3.w, acc[15]);
  }
  #pragma unroll
  for (int hh = 0; hh < 16; hh++)
    #pragma unroll
    for (int m = 32; m >= 1; m >>= 1) acc[hh] += __shfl_xor(acc[hh], m);
  __shared__ float red[4][16];
  __shared__ float hm[16];
  if (lane == 0) {
    #pragma unroll
    for (int hh = 0; hh < 16; hh++) red[w][hh] = acc[hh];
  }
  __syncthreads();
  if (t < 16) {
    const float s = red[0][t] + red[1][t] + red[2][t] + red[3][t] + b1[(size_t)e * 16 + t];
    hm[t] = 0.5f * s * (1.f + erff(s * 0.70710678118654752f));
  }
  __syncthreads();
  const float* w2e = w2 + (size_t)e * (16 * EDIM);
  float4 y = *(const float4*)(b2 + (size_t)e * EDIM + t * 4);
  const float4 res = *(const float4*)(out + (size_t)token * EDIM + t * 4);
  y.x += res.x; y.y += res.y; y.z += res.z; y.w += res.w;
  #pragma unroll
  for (int hh = 0; hh < 16; hh++) {
    const float hv = hm[hh];
    const float4 wv = *(const float4*)(w2e + (size_t)hh * EDIM + t * 4);
    y.x = fmaf(hv, wv.x, y.x);
    y.y = fmaf(hv, wv.y, y.y);
    y.z = fmaf(hv, wv.z, y.z);
    y.w = fmaf(hv, wv.w, y.w);
  }
  *(float4*)(out + (size_t)token * EDIM + t * 4) = y;
}

// ---------------- orchestration ------------------------------------------
extern "C" void kernel_launch(void* const* d_in, const int* in_sizes, int n_in,
                              void* d_out, int out_size, void* d_ws, size_t ws_size,
                              hipStream_t stream) {
  const float* x      = (const float*)d_in[0];
  const float* ln1_g  = (const float*)d_in[1];
  const float* ln1_b  = (const float*)d_in[2];
  const float* ln2_g  = (const float*)d_in[3];
  const float* ln2_b  = (const float*)d_in[4];
  const float* qkv_w  = (const float*)d_in[5];
  const float* qkv_b  = (const float*)d_in[6];
  const float* proj_w = (const float*)d_in[7];
  const float* proj_b = (const float*)d_in[8];
  const float* gate_w = (const float*)d_in[9];
  const float* gate_b = (const float*)d_in[10];
  const float* w1     = (const float*)d_in[11];
  const float* b1     = (const float*)d_in[12];
  const float* w2     = (const float*)d_in[13];
  const float* b2     = (const float*)d_in[14];
  float* out = (float*)d_out;

  char* p = (char*)d_ws;
  short* wTq = (short*)p; p += 3ull * 3072 * 1024 * 2;   // 18.9 MB (3 planes)
  short* wTp = (short*)p; p += 3ull * 1024 * 1024 * 2;   //  6.3 MB (3 planes)
  short* wTg = (short*)p; p += 2048ull * 1024 * 2;        //  4.2 MB (1 plane)
  short* h2  = (short*)p; p += (size_t)TOKENS * EDIM * 2; // 16.8 MB
  int* eidx  = (int*)p;   p += (size_t)TOKENS * 4;        // 32 KB
  p = (char*)(((size_t)p + 255) & ~(size_t)255);
  float* R1  = (float*)p; p += (size_t)TOKENS * EDIM * 4;   // 33.6 MB: h1f/attnof/h2f
  float* R2  = (float*)p; p += (size_t)TOKENS * 3072 * 4;   // 100.7 MB: qkvf/logits
  short* Kp  = (short*)p; p += 3ull * TOKENS * EDIM * 2;    // 50.3 MB (A planes / K planes)
  short* Vt  = (short*)p; p += 3ull * 64 * 64 * TSEQ * 2;   // 50.3 MB (V^T planes)
  float* h1f = R1;
  float* attnof = R1;
  float* h2f = R1;
  float* qkvf = R2;
  float* logits = R2;
  const size_t PSA = (size_t)TOKENS * EDIM;

  wsplit_kernel<<<dim3(3072 / 32, 1024 / 32), 256, 0, stream>>>(qkv_w, wTq, 1024, 3072);
  wsplit_kernel<<<dim3(1024 / 32, 1024 / 32), 256, 0, stream>>>(proj_w, wTp, 1024, 1024);
  wconv_kernel<<<dim3(2048 / 32, 1024 / 32), 256, 0, stream>>>(gate_w, wTg, 1024, 2048);

  // LN1 -> h1f (fp32)
  ln_kernel<<<TOKENS, 256, 0, stream>>>(x, ln1_g, ln1_b, nullptr, h1f);
  // pre-split h1f into 3 bf16 planes (Kp region; dead until ksplit)
  asplit_kernel<<<PSA / 8 / 256, 256, 0, stream>>>(h1f, Kp, PSA);
  // qkvf = h1 @ qkv_w + qkv_b  (hp, both operands pre-split)
  gemm_hp<0><<<dim3(3072 / 128, TOKENS / 128), 256, 0, stream>>>(
      Kp, PSA, wTq, (size_t)3072 * 1024, qkv_b, nullptr, qkvf, TOKENS, 3072, 1024);
  // pre-split K planes + transposed V planes (Kp overwritten; h1 planes dead)
  ksplit_kernel<<<TOKENS * 128 / 256, 256, 0, stream>>>(qkvf, Kp);
  vtrans_kernel<<<dim3(64, TSEQ / 32, 2), 256, 0, stream>>>(qkvf, Vt);
  // attention -> attnof (fp32; overwrites h1f region, h1f is dead)
  attn_hp<<<dim3(64, TSEQ / 64), 256, 0, stream>>>(qkvf, Kp, Vt, attnof);
  // pre-split attnof (Kp region again; K planes dead after attn)
  asplit_kernel<<<PSA / 8 / 256, 256, 0, stream>>>(attnof, Kp, PSA);
  // x1 = x + attno @ proj_w + proj_b -> out (fp32)
  gemm_hp<1><<<dim3(1024 / 128, TOKENS / 128), 256, 0, stream>>>(
      Kp, PSA, wTp, (size_t)1024 * 1024, proj_b, x, out, TOKENS, 1024, 1024);
  // LN2 -> h2 (bf16 plane) + h2f (fp32; overwrites attnof region, dead)
  ln_kernel<<<TOKENS, 256, 0, stream>>>(out, ln2_g, ln2_b, h2, h2f);
  // logits = h2 @ gate_w + gate_b (fp32; overwrites qkvf region, dead)
  gemm_bf16<<<dim3(2048 / 128, TOKENS / 128), 256, 0, stream>>>(
      h2, wTg, gate_b, logits, TOKENS, 2048, 1024);
  // argmax with exact fp32 rescore
  gate_argmax<<<TOKENS, 256, 0, stream>>>(logits, h2f, gate_w, gate_b, eidx);
  // MoE + residual -> d_out
  moe_kernel<<<TOKENS, 256, 0, stream>>>(h2f, eidx, w1, b1, w2, b2, out);
}

// Round 8
// 1160.864 us; speedup vs baseline: 1.7205x; 1.7205x over previous
//
#include <hip/hip_runtime.h>
#include <math.h>

#define TOKENS 8192
#define EDIM   1024
#define TSEQ   2048
#define NEXP   2048

typedef __attribute__((ext_vector_type(8))) short short8;
typedef __attribute__((ext_vector_type(4))) float f32x4;

__device__ __forceinline__ short f2bf(float f) {
  union { float f; unsigned u; } c; c.f = f;
  unsigned r = c.u + 0x7fffu + ((c.u >> 16) & 1u);
  return (short)(r >> 16);
}
__device__ __forceinline__ float bf2f(short h) {
  union { unsigned u; float f; } c; c.u = ((unsigned)(unsigned short)h) << 16;
  return c.f;
}
// split fp32 into 3 bf16 planes: a ≈ p0 + p1 + p2 (rel err ~2^-27)
__device__ __forceinline__ void split3(float a, short& p0, short& p1, short& p2) {
  p0 = f2bf(a);
  float r = a - bf2f(p0);
  p1 = f2bf(r);
  p2 = f2bf(r - bf2f(p1));
}
// split fp32 into 2 bf16 planes: a ≈ p0 + p1 (rel err ~2^-16)
__device__ __forceinline__ void split2(float a, short& p0, short& p1) {
  p0 = f2bf(a);
  p1 = f2bf(a - bf2f(p0));
}

// ---------------- LayerNorm: fp32 in -> optional bf16 plane + fp32 out ----
__global__ __launch_bounds__(256) void ln_kernel(const float* __restrict__ x,
    const float* __restrict__ g, const float* __restrict__ b,
    short* __restrict__ obf, float* __restrict__ of32)
{
  const int row = blockIdx.x;
  const int t = threadIdx.x, lane = t & 63, w = t >> 6;
  const float4 v = ((const float4*)(x + (size_t)row * EDIM))[t];
  __shared__ float lds[4];
  float s = v.x + v.y + v.z + v.w;
  #pragma unroll
  for (int m = 32; m >= 1; m >>= 1) s += __shfl_xor(s, m);
  if (lane == 0) lds[w] = s;
  __syncthreads();
  const float mu = (lds[0] + lds[1] + lds[2] + lds[3]) * (1.f / EDIM);
  __syncthreads();
  const float d0 = v.x - mu, d1 = v.y - mu, d2 = v.z - mu, d3 = v.w - mu;
  float sq = d0 * d0 + d1 * d1 + d2 * d2 + d3 * d3;
  #pragma unroll
  for (int m = 32; m >= 1; m >>= 1) sq += __shfl_xor(sq, m);
  if (lane == 0) lds[w] = sq;
  __syncthreads();
  const float var = (lds[0] + lds[1] + lds[2] + lds[3]) * (1.f / EDIM);
  const float rstd = rsqrtf(var + 1e-5f);
  const float4 gg = ((const float4*)g)[t];
  const float4 bb = ((const float4*)b)[t];
  const float y0 = d0 * rstd * gg.x + bb.x;
  const float y1 = d1 * rstd * gg.y + bb.y;
  const float y2 = d2 * rstd * gg.z + bb.z;
  const float y3 = d3 * rstd * gg.w + bb.w;
  if (obf) {
    unsigned long long pk =
        (unsigned long long)(unsigned short)f2bf(y0)
      | ((unsigned long long)(unsigned short)f2bf(y1) << 16)
      | ((unsigned long long)(unsigned short)f2bf(y2) << 32)
      | ((unsigned long long)(unsigned short)f2bf(y3) << 48);
    *(unsigned long long*)(obf + (size_t)row * EDIM + t * 4) = pk;
  }
  ((float4*)(of32 + (size_t)row * EDIM))[t] = make_float4(y0, y1, y2, y3);
}

// ---------------- W (KxN fp32) -> 3 bf16 planes Wt[p][N][K] ---------------
__global__ __launch_bounds__(256) void wsplit_kernel(const float* __restrict__ W,
    short* __restrict__ Wt, int K, int N)
{
  __shared__ float tile[32][33];
  const int n0 = blockIdx.x * 32, k0 = blockIdx.y * 32;
  const int tx = threadIdx.x & 31, ty = threadIdx.x >> 5;
  #pragma unroll
  for (int i = 0; i < 4; i++)
    tile[ty * 4 + i][tx] = W[(size_t)(k0 + ty * 4 + i) * N + n0 + tx];
  __syncthreads();
  const size_t PS = (size_t)N * K;
  #pragma unroll
  for (int i = 0; i < 4; i++) {
    short p0, p1, p2;
    split3(tile[tx][ty * 4 + i], p0, p1, p2);
    const size_t idx = (size_t)(n0 + ty * 4 + i) * K + k0 + tx;
    Wt[idx] = p0; Wt[PS + idx] = p1; Wt[2 * PS + idx] = p2;
  }
}

// ---------------- W (KxN fp32) -> single bf16 plane (NxK) -----------------
__global__ __launch_bounds__(256) void wconv_kernel(const float* __restrict__ W,
    short* __restrict__ Wt, int K, int N)
{
  __shared__ float tile[32][33];
  const int n0 = blockIdx.x * 32, k0 = blockIdx.y * 32;
  const int tx = threadIdx.x & 31, ty = threadIdx.x >> 5;
  #pragma unroll
  for (int i = 0; i < 4; i++)
    tile[ty * 4 + i][tx] = W[(size_t)(k0 + ty * 4 + i) * N + n0 + tx];
  __syncthreads();
  #pragma unroll
  for (int i = 0; i < 4; i++)
    Wt[(size_t)(n0 + ty * 4 + i) * K + k0 + tx] = f2bf(tile[tx][ty * 4 + i]);
}

// ---------------- flat fp32 [M*K] -> 3 bf16 planes (same layout) ----------
__global__ __launch_bounds__(256) void asplit_kernel(const float* __restrict__ src,
    short* __restrict__ dst, size_t PS)
{
  const size_t g8 = ((size_t)blockIdx.x * 256 + threadIdx.x) * 8;
  float v[8];
  *(float4*)&v[0] = *(const float4*)(src + g8);
  *(float4*)&v[4] = *(const float4*)(src + g8 + 4);
  short pl[3][8];
  #pragma unroll
  for (int j = 0; j < 8; j++) split3(v[j], pl[0][j], pl[1][j], pl[2][j]);
  *(short8*)(dst + g8)          = *(short8*)&pl[0][0];
  *(short8*)(dst + PS + g8)     = *(short8*)&pl[1][0];
  *(short8*)(dst + 2 * PS + g8) = *(short8*)&pl[2][0];
}

// ---------------- K section of qkvf -> 3 bf16 planes [3][8192][1024] ------
__global__ __launch_bounds__(256) void ksplit_kernel(const float* __restrict__ qkvf,
    short* __restrict__ Kp)
{
  const size_t gid = (size_t)blockIdx.x * 256 + threadIdx.x;
  const int tok = (int)(gid >> 7);
  const int c = (int)(gid & 127) * 8;
  const float* src = qkvf + (size_t)tok * 3072 + 1024 + c;
  float v[8];
  *(float4*)&v[0] = *(const float4*)src;
  *(float4*)&v[4] = *(const float4*)(src + 4);
  short pl[3][8];
  #pragma unroll
  for (int j = 0; j < 8; j++) split3(v[j], pl[0][j], pl[1][j], pl[2][j]);
  const size_t PS = (size_t)TOKENS * EDIM;
  const size_t dst = (size_t)tok * EDIM + c;
  *(short8*)(Kp + dst)          = *(short8*)&pl[0][0];
  *(short8*)(Kp + PS + dst)     = *(short8*)&pl[1][0];
  *(short8*)(Kp + 2 * PS + dst) = *(short8*)&pl[2][0];
}

// ---------------- V section -> 3 transposed planes [3][bh][d(64)][t(2048)]
__global__ __launch_bounds__(256) void vtrans_kernel(const float* __restrict__ qkvf,
    short* __restrict__ Vt)
{
  __shared__ float tile[32][33];
  const int bh = blockIdx.x;
  const int b = bh >> 4, h = bh & 15;
  const int t0 = blockIdx.y * 32;
  const int d0 = blockIdx.z * 32;
  const int tx = threadIdx.x & 31, ty = threadIdx.x >> 5;
  #pragma unroll
  for (int i = 0; i < 4; i++)
    tile[ty * 4 + i][tx] =
        qkvf[(size_t)(b * TSEQ + t0 + ty * 4 + i) * 3072 + 2048 + h * 64 + d0 + tx];
  __syncthreads();
  const size_t PS = (size_t)64 * 64 * TSEQ;
  #pragma unroll
  for (int i = 0; i < 4; i++) {
    short p0, p1, p2;
    split3(tile[tx][ty * 4 + i], p0, p1, p2);
    const size_t idx = (size_t)(bh * 64 + d0 + ty * 4 + i) * TSEQ + t0 + tx;
    Vt[idx] = p0; Vt[PS + idx] = p1; Vt[2 * PS + idx] = p2;
  }
}

// ---------------- high-precision GEMM: C = Aplanes * Bplanes^T + bias -----
// Round-4 version: unpadded XOR-swizzled LDS (49152 B), direct in-loop
// staging.  Register prefetch removed: hipcc caps at ~128 VGPR and spills
// the prefetch buffers (rounds 3 & 5: WRITE_SIZE 98MB -> >2GB).
template<int ADD_RES>
__global__ __launch_bounds__(256) void gemm_hp(const short* __restrict__ Ap, size_t astride,
    const short* __restrict__ Bp, size_t bstride, const float* __restrict__ bias,
    const float* __restrict__ resid, float* __restrict__ outp,
    int M, int N, int K)
{
  __shared__ short As[3][128][32];   // 24576 B
  __shared__ short Bs[3][128][32];   // 24576 B
  const int m0 = blockIdx.y * 128, n0 = blockIdx.x * 128;
  const int t = threadIdx.x;
  const int lane = t & 63, w = t >> 6;
  const int wm = w >> 1, wn = w & 1;
  const int lo = lane & 15, hi = lane >> 4;
  const int rr = t >> 2;                            // staging row (0..63, +u*64)
  const int cj = t & 3;                             // staged chunk id
  const int crw = (rr & 3) ^ ((rr >> 2) & 3);       // row swizzle code (u-invariant)
  const int wc8 = ((cj ^ crw)) * 8;                 // swizzled write offset (shorts)
  const int rc8 = ((hi ^ (lo & 3) ^ ((lo >> 2) & 3))) * 8;  // swizzled read offset
  f32x4 acc[4][4];
  #pragma unroll
  for (int i = 0; i < 4; i++)
    #pragma unroll
    for (int j = 0; j < 4; j++)
      acc[i][j] = (f32x4){0.f, 0.f, 0.f, 0.f};

  for (int k0 = 0; k0 < K; k0 += 32) {
    #pragma unroll
    for (int p = 0; p < 3; p++)
      #pragma unroll
      for (int u = 0; u < 2; u++) {
        *(uint4*)&As[p][u * 64 + rr][wc8] =
            *(const uint4*)(Ap + (size_t)p * astride + (size_t)(m0 + u * 64 + rr) * K + k0 + cj * 8);
        *(uint4*)&Bs[p][u * 64 + rr][wc8] =
            *(const uint4*)(Bp + (size_t)p * bstride + (size_t)(n0 + u * 64 + rr) * K + k0 + cj * 8);
      }
    __syncthreads();
    short8 af[3][4], bf[3][4];
    #pragma unroll
    for (int p = 0; p < 3; p++)
      #pragma unroll
      for (int i = 0; i < 4; i++) {
        af[p][i] = *(const short8*)(&As[p][wm * 64 + i * 16 + lo][rc8]);
        bf[p][i] = *(const short8*)(&Bs[p][wn * 64 + i * 16 + lo][rc8]);
      }
    __builtin_amdgcn_s_setprio(1);
    #pragma unroll
    for (int i = 0; i < 4; i++)
      #pragma unroll
      for (int j = 0; j < 4; j++) {
        acc[i][j] = __builtin_amdgcn_mfma_f32_16x16x32_bf16(af[0][i], bf[0][j], acc[i][j], 0, 0, 0);
        acc[i][j] = __builtin_amdgcn_mfma_f32_16x16x32_bf16(af[0][i], bf[1][j], acc[i][j], 0, 0, 0);
        acc[i][j] = __builtin_amdgcn_mfma_f32_16x16x32_bf16(af[1][i], bf[0][j], acc[i][j], 0, 0, 0);
        acc[i][j] = __builtin_amdgcn_mfma_f32_16x16x32_bf16(af[1][i], bf[1][j], acc[i][j], 0, 0, 0);
        acc[i][j] = __builtin_amdgcn_mfma_f32_16x16x32_bf16(af[0][i], bf[2][j], acc[i][j], 0, 0, 0);
        acc[i][j] = __builtin_amdgcn_mfma_f32_16x16x32_bf16(af[2][i], bf[0][j], acc[i][j], 0, 0, 0);
      }
    __builtin_amdgcn_s_setprio(0);
    __syncthreads();
  }
  #pragma unroll
  for (int i = 0; i < 4; i++)
    #pragma unroll
    for (int j = 0; j < 4; j++)
      #pragma unroll
      for (int r = 0; r < 4; r++) {
        const int gm = m0 + wm * 64 + i * 16 + hi * 4 + r;
        const int gn = n0 + wn * 64 + j * 16 + lo;
        float v = acc[i][j][r] + bias[gn];
        if (ADD_RES) v += resid[(size_t)gm * N + gn];
        outp[(size_t)gm * N + gn] = v;
      }
}

// ---------------- high-precision flash attention (causal) -----------------
__global__ __launch_bounds__(256) void attn_hp(const float* __restrict__ qkvf,
    const short* __restrict__ Kp, const short* __restrict__ Vt,
    float* __restrict__ attno)
{
  const int bh = blockIdx.x;
  const int b = bh >> 4, h = bh & 15;
  const int qb0 = blockIdx.y * 64;
  const int t = threadIdx.x, lane = t & 63, w = t >> 6;
  const int lo = lane & 15, hi = lane >> 4;
  __shared__ short Ks[3][32][72];    // 13824 B
  __shared__ short Vs[3][64][40];    // 15360 B, transposed: Vs[p][dim][key]
  __shared__ short Ps[2][4][16][40]; // 10240 B -> total 39424 B: 4 blocks/CU
  const size_t base = (size_t)b * TSEQ * 3072;
  const size_t PSK = (size_t)TOKENS * EDIM;
  const size_t PSV = (size_t)64 * 64 * TSEQ;
  const int qw0 = qb0 + w * 16;
  short8 qf[3][2];
  #pragma unroll
  for (int c = 0; c < 2; c++) {
    const float* qp = qkvf + base + (size_t)(qw0 + lo) * 3072 + h * 64 + c * 32 + hi * 8;
    float qv[8];
    *(float4*)&qv[0] = *(const float4*)qp;
    *(float4*)&qv[4] = *(const float4*)(qp + 4);
    #pragma unroll
    for (int j = 0; j < 8; j++) {
      short s0, s1, s2;
      split3(qv[j] * 0.125f, s0, s1, s2);   // exact pow2 pre-scale
      qf[0][c][j] = s0; qf[1][c][j] = s1; qf[2][c][j] = s2;
    }
  }
  float l_r[4] = {0.f, 0.f, 0.f, 0.f};
  f32x4 o[4];
  #pragma unroll
  for (int nb = 0; nb < 4; nb++) o[nb] = (f32x4){0.f, 0.f, 0.f, 0.f};

  const int key = t >> 3, c0 = (t & 7) * 8;
  const int dv = t >> 2, kc = (t & 3) * 8;
  const short* kbase = Kp + (size_t)(b * TSEQ + key) * EDIM + h * 64 + c0;
  const short* vbase = Vt + (size_t)(bh * 64 + dv) * TSEQ + kc;
  short8 kreg0 = *(const short8*)kbase;
  short8 kreg1 = *(const short8*)(kbase + PSK);
  short8 kreg2 = *(const short8*)(kbase + 2 * PSK);
  short8 vreg0 = *(const short8*)vbase;
  short8 vreg1 = *(const short8*)(vbase + PSV);
  short8 vreg2 = *(const short8*)(vbase + 2 * PSV);

  const int ntiles = 2 * blockIdx.y + 2;
  for (int tile = 0; tile < ntiles; tile++) {
    const int kt0 = tile * 32;
    __syncthreads();                 // prior compute done reading LDS
    *(short8*)&Ks[0][key][c0] = kreg0;
    *(short8*)&Ks[1][key][c0] = kreg1;
    *(short8*)&Ks[2][key][c0] = kreg2;
    *(short8*)&Vs[0][dv][kc] = vreg0;
    *(short8*)&Vs[1][dv][kc] = vreg1;
    *(short8*)&Vs[2][dv][kc] = vreg2;
    __syncthreads();                 // tile staged
    if (tile + 1 < ntiles) {         // prefetch next tile; latency hides under MFMA
      const short* kp = kbase + (size_t)(tile + 1) * 32 * EDIM;
      const short* vp = vbase + (tile + 1) * 32;
      kreg0 = *(const short8*)kp;
      kreg1 = *(const short8*)(kp + PSK);
      kreg2 = *(const short8*)(kp + 2 * PSK);
      vreg0 = *(const short8*)vp;
      vreg1 = *(const short8*)(vp + PSV);
      vreg2 = *(const short8*)(vp + 2 * PSV);
    }
    if (kt0 <= qw0 + 15) {
      f32x4 s[2];
      __builtin_amdgcn_s_setprio(1);
      #pragma unroll
      for (int kb = 0; kb < 2; kb++) {
        f32x4 z = (f32x4){0.f, 0.f, 0.f, 0.f};
        #pragma unroll
        for (int c = 0; c < 2; c++) {
          const short8 kf0 = *(const short8*)(&Ks[0][kb * 16 + lo][c * 32 + hi * 8]);
          const short8 kf1 = *(const short8*)(&Ks[1][kb * 16 + lo][c * 32 + hi * 8]);
          const short8 kf2 = *(const short8*)(&Ks[2][kb * 16 + lo][c * 32 + hi * 8]);
          z = __builtin_amdgcn_mfma_f32_16x16x32_bf16(qf[0][c], kf0, z, 0, 0, 0);
          z = __builtin_amdgcn_mfma_f32_16x16x32_bf16(qf[0][c], kf1, z, 0, 0, 0);
          z = __builtin_amdgcn_mfma_f32_16x16x32_bf16(qf[1][c], kf0, z, 0, 0, 0);
          z = __builtin_amdgcn_mfma_f32_16x16x32_bf16(qf[1][c], kf1, z, 0, 0, 0);
          z = __builtin_amdgcn_mfma_f32_16x16x32_bf16(qf[0][c], kf2, z, 0, 0, 0);
          z = __builtin_amdgcn_mfma_f32_16x16x32_bf16(qf[2][c], kf0, z, 0, 0, 0);
        }
        s[kb] = z;
      }
      __builtin_amdgcn_s_setprio(0);
      #pragma unroll
      for (int r = 0; r < 4; r++) {
        const int qg = qw0 + hi * 4 + r;
        #pragma unroll
        for (int kb = 0; kb < 2; kb++) {
          const int kg = kt0 + kb * 16 + lo;
          float v = s[kb][r];
          v = (kg > qg) ? -1e30f : v;
          const float pv = __expf(v);
          s[kb][r] = pv;
          l_r[r] += pv;
        }
      }
      #pragma unroll
      for (int kb = 0; kb < 2; kb++)
        #pragma unroll
        for (int r = 0; r < 4; r++) {
          short p0, p1;
          split2(s[kb][r], p0, p1);
          Ps[0][w][hi * 4 + r][kb * 16 + lo] = p0;
          Ps[1][w][hi * 4 + r][kb * 16 + lo] = p1;
        }
      __threadfence_block();   // intra-wave LDS RAW ordering (C->A layout)
      const short8 pf0 = *(const short8*)(&Ps[0][w][lo][hi * 8]);
      const short8 pf1 = *(const short8*)(&Ps[1][w][lo][hi * 8]);
      __builtin_amdgcn_s_setprio(1);
      #pragma unroll
      for (int nb = 0; nb < 4; nb++) {
        const short8 vb0 = *(const short8*)(&Vs[0][nb * 16 + lo][hi * 8]);
        const short8 vb1 = *(const short8*)(&Vs[1][nb * 16 + lo][hi * 8]);
        const short8 vb2 = *(const short8*)(&Vs[2][nb * 16 + lo][hi * 8]);
        o[nb] = __builtin_amdgcn_mfma_f32_16x16x32_bf16(pf0, vb0, o[nb], 0, 0, 0);
        o[nb] = __builtin_amdgcn_mfma_f32_16x16x32_bf16(pf0, vb1, o[nb], 0, 0, 0);
        o[nb] = __builtin_amdgcn_mfma_f32_16x16x32_bf16(pf1, vb0, o[nb], 0, 0, 0);
        o[nb] = __builtin_amdgcn_mfma_f32_16x16x32_bf16(pf1, vb1, o[nb], 0, 0, 0);
        o[nb] = __builtin_amdgcn_mfma_f32_16x16x32_bf16(pf0, vb2, o[nb], 0, 0, 0);
      }
      __builtin_amdgcn_s_setprio(0);
    }
  }
  // deferred l reduction: one 4-step shuffle per r for the whole block
  #pragma unroll
  for (int r = 0; r < 4; r++)
    #pragma unroll
    for (int mm = 8; mm >= 1; mm >>= 1) l_r[r] += __shfl_xor(l_r[r], mm);
  #pragma unroll
  for (int nb = 0; nb < 4; nb++)
    #pragma unroll
    for (int r = 0; r < 4; r++) {
      const int tok = qw0 + hi * 4 + r;
      attno[(size_t)(b * TSEQ + tok) * EDIM + h * 64 + nb * 16 + lo] = o[nb][r] / l_r[r];
    }
}

// ---------------- plain bf16 GEMM (gate logits): fp32 out ----------------
__global__ __launch_bounds__(256) void gemm_bf16(const short* __restrict__ A,
    const short* __restrict__ Bt, const float* __restrict__ bias,
    float* __restrict__ outp, int M, int N, int K)
{
  __shared__ short As[128][72];
  __shared__ short Bs[128][72];
  const int m0 = blockIdx.y * 128, n0 = blockIdx.x * 128;
  const int t = threadIdx.x;
  const int lane = t & 63, w = t >> 6;
  const int wm = w >> 1, wn = w & 1;
  const int lo = lane & 15, hi = lane >> 4;
  f32x4 acc[4][4];
  #pragma unroll
  for (int i = 0; i < 4; i++)
    #pragma unroll
    for (int j = 0; j < 4; j++)
      acc[i][j] = (f32x4){0.f, 0.f, 0.f, 0.f};
  for (int k0 = 0; k0 < K; k0 += 64) {
    #pragma unroll
    for (int c = 0; c < 4; c++) {
      const int cc = t + 256 * c;
      const int row = cc >> 3, col = (cc & 7) * 8;
      *(uint4*)(&As[row][col]) = *(const uint4*)(A + (size_t)(m0 + row) * K + k0 + col);
      *(uint4*)(&Bs[row][col]) = *(const uint4*)(Bt + (size_t)(n0 + row) * K + k0 + col);
    }
    __syncthreads();
    #pragma unroll
    for (int kk = 0; kk < 2; kk++) {
      short8 af[4], bf[4];
      #pragma unroll
      for (int i = 0; i < 4; i++) {
        af[i] = *(const short8*)(&As[wm * 64 + i * 16 + lo][kk * 32 + hi * 8]);
        bf[i] = *(const short8*)(&Bs[wn * 64 + i * 16 + lo][kk * 32 + hi * 8]);
      }
      #pragma unroll
      for (int i = 0; i < 4; i++)
        #pragma unroll
        for (int j = 0; j < 4; j++)
          acc[i][j] = __builtin_amdgcn_mfma_f32_16x16x32_bf16(af[i], bf[j], acc[i][j], 0, 0, 0);
    }
    __syncthreads();
  }
  #pragma unroll
  for (int i = 0; i < 4; i++)
    #pragma unroll
    for (int j = 0; j < 4; j++)
      #pragma unroll
      for (int r = 0; r < 4; r++) {
        const int gm = m0 + wm * 64 + i * 16 + hi * 4 + r;
        const int gn = n0 + wn * 64 + j * 16 + lo;
        outp[(size_t)gm * N + gn] = acc[i][j][r] + bias[gn];
      }
}

// ---------------- zero expert counters ------------------------------------
__global__ __launch_bounds__(256) void zero_kernel(int* __restrict__ cnt,
    int* __restrict__ cursor)
{
  const int i = blockIdx.x * 256 + threadIdx.x;
  cnt[i] = 0; cursor[i] = 0;
}

// ---------------- gate argmax with exact fp32 rescore + expert count ------
__global__ __launch_bounds__(256) void gate_argmax(const float* __restrict__ logits,
    const float* __restrict__ h2f, const float* __restrict__ gw,
    const float* __restrict__ gb, int* __restrict__ eidx, int* __restrict__ ecnt)
{
  const int token = blockIdx.x;
  const int t = threadIdx.x, lane = t & 63, w = t >> 6;
  const float* row = logits + (size_t)token * NEXP;
  float bm = -1e30f;
  #pragma unroll
  for (int c = 0; c < 8; c++) bm = fmaxf(bm, row[t + 256 * c]);
  #pragma unroll
  for (int m = 32; m >= 1; m >>= 1) bm = fmaxf(bm, __shfl_xor(bm, m));
  __shared__ float wred[4];
  __shared__ int cnt;
  __shared__ int cand[16];
  __shared__ float sred[4];
  if (t == 0) cnt = 0;
  if (lane == 0) wred[w] = bm;
  __syncthreads();
  const float maxv = fmaxf(fmaxf(wred[0], wred[1]), fmaxf(wred[2], wred[3]));
  const float thr = maxv - 0.03f;
  #pragma unroll
  for (int c = 0; c < 8; c++) {
    const int e = t + 256 * c;
    if (row[e] > thr) {
      const int p = atomicAdd(&cnt, 1);
      if (p < 16) cand[p] = e;
    }
  }
  __syncthreads();
  const int nc = cnt < 16 ? cnt : 16;
  if (nc == 1) {
    if (t == 0) { eidx[token] = cand[0]; atomicAdd(&ecnt[cand[0]], 1); }
    return;
  }
  const float* xr = h2f + (size_t)token * EDIM;
  int best = NEXP; float bs = -1e30f;
  for (int c = 0; c < nc; c++) {
    const int e = cand[c];
    float p = 0.f;
    #pragma unroll
    for (int ii = 0; ii < 4; ii++) {
      const int i = t + 256 * ii;
      p += xr[i] * gw[(size_t)i * NEXP + e];
    }
    #pragma unroll
    for (int m = 32; m >= 1; m >>= 1) p += __shfl_xor(p, m);
    if (lane == 0) sred[w] = p;
    __syncthreads();
    const float s = sred[0] + sred[1] + sred[2] + sred[3] + gb[e];
    if (s > bs || (s == bs && e < best)) { bs = s; best = e; }
    __syncthreads();
  }
  if (t == 0) { eidx[token] = best; atomicAdd(&ecnt[best], 1); }
}

// ---------------- exclusive scan of 2048 expert counts (1 block) ----------
__global__ __launch_bounds__(256) void scan_kernel(const int* __restrict__ cnt,
    int* __restrict__ off)
{
  __shared__ int ws[256];
  const int t = threadIdx.x;
  int v[8]; int s = 0;
  #pragma unroll
  for (int j = 0; j < 8; j++) { v[j] = s; s += cnt[t * 8 + j]; }
  ws[t] = s;
  __syncthreads();
  for (int d = 1; d < 256; d <<= 1) {
    int y = (t >= d) ? ws[t - d] : 0;
    __syncthreads();
    ws[t] += y;
    __syncthreads();
  }
  const int base = (t > 0) ? ws[t - 1] : 0;
  #pragma unroll
  for (int j = 0; j < 8; j++) off[t * 8 + j] = base + v[j];
}

// ---------------- scatter tokens into per-expert lists --------------------
__global__ __launch_bounds__(256) void scatter_kernel(const int* __restrict__ eidx,
    const int* __restrict__ off, int* __restrict__ cursor, int* __restrict__ tlist)
{
  const int token = blockIdx.x * 256 + threadIdx.x;
  const int e = eidx[token];
  const int pos = atomicAdd(&cursor[e], 1);
  tlist[off[e] + pos] = token;
}

// ---------------- MoE expert apply, batched by expert ---------------------
// One block per expert; weights hit L2 after the first token (weight HBM
// traffic drops 1.07 GB -> ~268 MB).  Per-token math identical to before.
__global__ __launch_bounds__(256) void moe_apply(const float* __restrict__ h2f,
    const int* __restrict__ ecnt, const int* __restrict__ off,
    const int* __restrict__ tlist, const float* __restrict__ w1,
    const float* __restrict__ b1, const float* __restrict__ w2,
    const float* __restrict__ b2, float* __restrict__ out)
{
  const int e = blockIdx.x;
  const int nt = ecnt[e];
  if (nt == 0) return;
  const int base = off[e];
  const int t = threadIdx.x, lane = t & 63, w = t >> 6;
  const float* w1e = w1 + (size_t)e * (EDIM * 16);
  const float* w2e = w2 + (size_t)e * (16 * EDIM);
  __shared__ float red[4][16];
  __shared__ float hm[16];
  for (int it = 0; it < nt; it++) {
    const int token = tlist[base + it];
    const float* xr = h2f + (size_t)token * EDIM;
    float acc[16];
    #pragma unroll
    for (int hh = 0; hh < 16; hh++) acc[hh] = 0.f;
    #pragma unroll
    for (int ii = 0; ii < 4; ii++) {
      const int i = t + 256 * ii;
      const float xi = xr[i];
      const float4* wr = (const float4*)(w1e + (size_t)i * 16);
      const float4 r0 = wr[0], r1 = wr[1], r2 = wr[2], r3 = wr[3];
      acc[0] = fmaf(xi, r0.x, acc[0]);  acc[1] = fmaf(xi, r0.y, acc[1]);
      acc[2] = fmaf(xi, r0.z, acc[2]);  acc[3] = fmaf(xi, r0.w, acc[3]);
      acc[4] = fmaf(xi, r1.x, acc[4]);  acc[5] = fmaf(xi, r1.y, acc[5]);
      acc[6] = fmaf(xi, r1.z, acc[6]);  acc[7] = fmaf(xi, r1.w, acc[7]);
      acc[8] = fmaf(xi, r2.x, acc[8]);  acc[9] = fmaf(xi, r2.y, acc[9]);
      acc[10] = fmaf(xi, r2.z, acc[10]); acc[11] = fmaf(xi, r2.w, acc[11]);
      acc[12] = fmaf(xi, r3.x, acc[12]); acc[13] = fmaf(xi, r3.y, acc[13]);
      acc[14] = fmaf(xi, r3.z, acc[14]); acc[15] = fmaf(xi, r3.w, acc[15]);
    }
    #pragma unroll
    for (int hh = 0; hh < 16; hh++)
      #pragma unroll
      for (int m = 32; m >= 1; m >>= 1) acc[hh] += __shfl_xor(acc[hh], m);
    if (lane == 0) {
      #pragma unroll
      for (int hh = 0; hh < 16; hh++) red[w][hh] = acc[hh];
    }
    __syncthreads();
    if (t < 16) {
      const float s = red[0][t] + red[1][t] + red[2][t] + red[3][t] + b1[(size_t)e * 16 + t];
      hm[t] = 0.5f * s * (1.f + erff(s * 0.70710678118654752f));
    }
    __syncthreads();
    float4 y = *(const float4*)(b2 + (size_t)e * EDIM + t * 4);
    const float4 res = *(const float4*)(out + (size_t)token * EDIM + t * 4);
    y.x += res.x; y.y += res.y; y.z += res.z; y.w += res.w;
    #pragma unroll
    for (int hh = 0; hh < 16; hh++) {
      const float hv = hm[hh];
      const float4 wv = *(const float4*)(w2e + (size_t)hh * EDIM + t * 4);
      y.x = fmaf(hv, wv.x, y.x);
      y.y = fmaf(hv, wv.y, y.y);
      y.z = fmaf(hv, wv.z, y.z);
      y.w = fmaf(hv, wv.w, y.w);
    }
    *(float4*)(out + (size_t)token * EDIM + t * 4) = y;
    __syncthreads();   // all done with red/hm before next token overwrites
  }
}

// ---------------- orchestration ------------------------------------------
extern "C" void kernel_launch(void* const* d_in, const int* in_sizes, int n_in,
                              void* d_out, int out_size, void* d_ws, size_t ws_size,
                              hipStream_t stream) {
  const float* x      = (const float*)d_in[0];
  const float* ln1_g  = (const float*)d_in[1];
  const float* ln1_b  = (const float*)d_in[2];
  const float* ln2_g  = (const float*)d_in[3];
  const float* ln2_b  = (const float*)d_in[4];
  const float* qkv_w  = (const float*)d_in[5];
  const float* qkv_b  = (const float*)d_in[6];
  const float* proj_w = (const float*)d_in[7];
  const float* proj_b = (const float*)d_in[8];
  const float* gate_w = (const float*)d_in[9];
  const float* gate_b = (const float*)d_in[10];
  const float* w1     = (const float*)d_in[11];
  const float* b1     = (const float*)d_in[12];
  const float* w2     = (const float*)d_in[13];
  const float* b2     = (const float*)d_in[14];
  float* out = (float*)d_out;

  // Workspace layout is byte-identical to the round-5 (passing) kernel.
  // Routing buffers are aliased into the Vt region, which is dead by the
  // time routing runs (vtrans/attn_hp finished; routing starts after
  // gemm_bf16).  This removes the only identified container-failure risk
  // (workspace growth past ws_size).
  char* p = (char*)d_ws;
  short* wTq = (short*)p; p += 3ull * 3072 * 1024 * 2;   // 18.9 MB (3 planes)
  short* wTp = (short*)p; p += 3ull * 1024 * 1024 * 2;   //  6.3 MB (3 planes)
  short* wTg = (short*)p; p += 2048ull * 1024 * 2;        //  4.2 MB (1 plane)
  short* h2  = (short*)p; p += (size_t)TOKENS * EDIM * 2; // 16.8 MB
  int* eidx  = (int*)p;   p += (size_t)TOKENS * 4;        // 32 KB
  p = (char*)(((size_t)p + 255) & ~(size_t)255);
  float* R1  = (float*)p; p += (size_t)TOKENS * EDIM * 4;   // 33.6 MB: h1f/attnof/h2f
  float* R2  = (float*)p; p += (size_t)TOKENS * 3072 * 4;   // 100.7 MB: qkvf/logits
  short* Kp  = (short*)p; p += 3ull * TOKENS * EDIM * 2;    // 50.3 MB (A planes / K planes)
  short* Vt  = (short*)p; p += 3ull * 64 * 64 * TSEQ * 2;   // 50.3 MB (V^T planes)
  float* h1f = R1;
  float* attnof = R1;
  float* h2f = R1;
  float* qkvf = R2;
  float* logits = R2;
  // routing buffers alias Vt (dead after attn_hp; routing runs later)
  int* ecnt  = (int*)Vt;
  int* eoff  = ecnt + NEXP;
  int* ecur  = eoff + NEXP;
  int* tlist = ecur + NEXP;
  const size_t PSA = (size_t)TOKENS * EDIM;

  wsplit_kernel<<<dim3(3072 / 32, 1024 / 32), 256, 0, stream>>>(qkv_w, wTq, 1024, 3072);
  wsplit_kernel<<<dim3(1024 / 32, 1024 / 32), 256, 0, stream>>>(proj_w, wTp, 1024, 1024);
  wconv_kernel<<<dim3(2048 / 32, 1024 / 32), 256, 0, stream>>>(gate_w, wTg, 1024, 2048);

  // LN1 -> h1f (fp32)
  ln_kernel<<<TOKENS, 256, 0, stream>>>(x, ln1_g, ln1_b, nullptr, h1f);
  // pre-split h1f into 3 bf16 planes (Kp region; dead until ksplit)
  asplit_kernel<<<PSA / 8 / 256, 256, 0, stream>>>(h1f, Kp, PSA);
  // qkvf = h1 @ qkv_w + qkv_b  (hp, both operands pre-split)
  gemm_hp<0><<<dim3(3072 / 128, TOKENS / 128), 256, 0, stream>>>(
      Kp, PSA, wTq, (size_t)3072 * 1024, qkv_b, nullptr, qkvf, TOKENS, 3072, 1024);
  // pre-split K planes + transposed V planes (Kp overwritten; h1 planes dead)
  ksplit_kernel<<<TOKENS * 128 / 256, 256, 0, stream>>>(qkvf, Kp);
  vtrans_kernel<<<dim3(64, TSEQ / 32, 2), 256, 0, stream>>>(qkvf, Vt);
  // attention -> attnof (fp32; overwrites h1f region, h1f is dead)
  attn_hp<<<dim3(64, TSEQ / 64), 256, 0, stream>>>(qkvf, Kp, Vt, attnof);
  // pre-split attnof (Kp region again; K planes dead after attn)
  asplit_kernel<<<PSA / 8 / 256, 256, 0, stream>>>(attnof, Kp, PSA);
  // x1 = x + attno @ proj_w + proj_b -> out (fp32)
  gemm_hp<1><<<dim3(1024 / 128, TOKENS / 128), 256, 0, stream>>>(
      Kp, PSA, wTp, (size_t)1024 * 1024, proj_b, x, out, TOKENS, 1024, 1024);
  // LN2 -> h2 (bf16 plane) + h2f (fp32; overwrites attnof region, dead)
  ln_kernel<<<TOKENS, 256, 0, stream>>>(out, ln2_g, ln2_b, h2, h2f);
  // logits = h2 @ gate_w + gate_b (fp32; overwrites qkvf region, dead)
  gemm_bf16<<<dim3(2048 / 128, TOKENS / 128), 256, 0, stream>>>(
      h2, wTg, gate_b, logits, TOKENS, 2048, 1024);
  // expert routing: argmax (+count) -> scan -> scatter  (buffers in Vt alias)
  zero_kernel<<<NEXP / 256, 256, 0, stream>>>(ecnt, ecur);
  gate_argmax<<<TOKENS, 256, 0, stream>>>(logits, h2f, gate_w, gate_b, eidx, ecnt);
  scan_kernel<<<1, 256, 0, stream>>>(ecnt, eoff);
  scatter_kernel<<<TOKENS / 256, 256, 0, stream>>>(eidx, eoff, ecur, tlist);
  // MoE batched by expert + residual -> d_out
  moe_apply<<<NEXP, 256, 0, stream>>>(h2f, ecnt, eoff, tlist, w1, b1, w2, b2, out);
}